// Round 11
// baseline (566.196 us; speedup 1.0000x reference)
//
#include <hip/hip_runtime.h>
#include <hip/hip_bf16.h>

#define LRELU_ALPHA 0.2f

typedef __attribute__((ext_vector_type(8))) __bf16 bf16x8;
typedef __attribute__((ext_vector_type(4))) float f32x4;
typedef __attribute__((ext_vector_type(8))) unsigned short u16x8;
typedef __attribute__((ext_vector_type(4))) unsigned short u16x4;

__device__ __forceinline__ unsigned short f2bf(float f) {
  unsigned int u = __float_as_uint(f);
  u += 0x7fffu + ((u >> 16) & 1u);   // round-to-nearest-even
  return (unsigned short)(u >> 16);
}

// ---------------- fp32 tiled GEMM: wh1 = x @ W1 ----------------
__global__ __launch_bounds__(256) void gemm_f32_k(
    const float* __restrict__ A, const float* __restrict__ B,
    float* __restrict__ C, int M, int K, int Ncols)
{
  __shared__ float As[128][17];
  __shared__ float Bs[16][65];
  int t = threadIdx.x;
  int row0 = blockIdx.x * 128;
  int col0 = blockIdx.y * 64;
  int ty = t >> 4, tx = t & 15;
  float acc[8][4];
#pragma unroll
  for (int i = 0; i < 8; ++i)
#pragma unroll
    for (int j = 0; j < 4; ++j) acc[i][j] = 0.f;

  for (int kt = 0; kt < K; kt += 16) {
    __syncthreads();
    {
      int r = t >> 1, h = t & 1;
      const float4* src = (const float4*)(A + (size_t)(row0 + r) * K + kt + h * 8);
      float4 v0 = src[0], v1 = src[1];
      float* dst = &As[r][h * 8];
      dst[0]=v0.x; dst[1]=v0.y; dst[2]=v0.z; dst[3]=v0.w;
      dst[4]=v1.x; dst[5]=v1.y; dst[6]=v1.z; dst[7]=v1.w;
    }
    {
      int kr = t >> 4, seg = t & 15;
      const float4* src = (const float4*)(B + (size_t)(kt + kr) * Ncols + col0 + seg * 4);
      float4 v = src[0];
      float* dst = &Bs[kr][seg * 4];
      dst[0]=v.x; dst[1]=v.y; dst[2]=v.z; dst[3]=v.w;
    }
    __syncthreads();
#pragma unroll
    for (int k = 0; k < 16; ++k) {
      float bb[4];
#pragma unroll
      for (int j = 0; j < 4; ++j) bb[j] = Bs[k][tx * 4 + j];
#pragma unroll
      for (int i = 0; i < 8; ++i) {
        float aa = As[ty * 8 + i][k];
#pragma unroll
        for (int j = 0; j < 4; ++j) acc[i][j] = fmaf(aa, bb[j], acc[i][j]);
      }
    }
  }
#pragma unroll
  for (int i = 0; i < 8; ++i) {
    float4 v = make_float4(acc[i][0], acc[i][1], acc[i][2], acc[i][3]);
    *(float4*)(C + (size_t)(row0 + ty * 8 + i) * Ncols + col0 + tx * 4) = v;
  }
}

// ---------------- e1/e2 vectors: wave per row ----------------
__global__ __launch_bounds__(256) void calc_e_k(
    const float* __restrict__ Wh, const float* __restrict__ a,
    float* __restrict__ e1, float* __restrict__ e2, int F)
{
  int row = blockIdx.x * 4 + (threadIdx.x >> 6);
  int l = threadIdx.x & 63;
  const float* r = Wh + (size_t)row * F;
  float s1 = 0.f, s2 = 0.f;
  for (int f = l; f < F; f += 64) {
    float v = r[f];
    s1 += v * a[f];
    s2 += v * a[F + f];
  }
#pragma unroll
  for (int off = 32; off; off >>= 1) {
    s1 += __shfl_down(s1, off);
    s2 += __shfl_down(s2, off);
  }
  if (l == 0) { e1[row] = s1; e2[row] = s2; }
}

// ---------------- transpose + fp32->bf16: out[c][r] = bf16(in[r][c]) ----------------
__global__ void transpose_bf16_k(const float* __restrict__ in, unsigned short* __restrict__ out,
                                 int R, int Cc)
{
  __shared__ float tile[32][33];
  int tx = threadIdx.x, ty = threadIdx.y;
  int c0 = blockIdx.x * 32, r0 = blockIdx.y * 32;
  int c = c0 + tx;
  if (c < Cc) {
    for (int i = ty; i < 32; i += 8)
      tile[i][tx] = in[(size_t)(r0 + i) * Cc + c];
  }
  __syncthreads();
  int r = r0 + tx;
  for (int i = ty; i < 32; i += 8) {
    int cc = c0 + i;
    if (cc < Cc)
      out[(size_t)cc * R + r] = f2bf(tile[tx][i]);
  }
}

// ---------------- rowsum + adj bit-pack: sinv[i] = 1/sum_j mask*exp(lrelu(e1+e2)) ----------------
// One block per row; the only kernel that reads adj (256 MB). Packs bits (8 MB)
// for everything downstream. No max-shift (verified identical numerics R3-R10).
__global__ __launch_bounds__(256) void rowsum_pack_k(
    const int* __restrict__ adj, const float* __restrict__ e1,
    const float* __restrict__ e2, unsigned* __restrict__ bits,
    float* __restrict__ sinv)
{
  __shared__ float red[4];
  int i = blockIdx.x, t = threadIdx.x;
  const int4* arow = (const int4*)(adj + (size_t)i * 8192);
  unsigned* brow = bits + (size_t)i * 256;
  float e1i = e1[i];
  float s = 0.f;
#pragma unroll
  for (int it = 0; it < 8; ++it) {
    int j4 = t + it * 256;
    int4 a4 = arow[j4];
    float4 ev = *(const float4*)(e2 + j4 * 4);
    unsigned n = (unsigned)(a4.x > 0) | ((unsigned)(a4.y > 0) << 1)
               | ((unsigned)(a4.z > 0) << 2) | ((unsigned)(a4.w > 0) << 3);
    unsigned v = n << ((t & 7) * 4);
    v |= __shfl_xor(v, 1);
    v |= __shfl_xor(v, 2);
    v |= __shfl_xor(v, 4);
    if ((t & 7) == 0) brow[it * 32 + (t >> 3)] = v;
    float e;
    e = e1i + ev.x; e = e > 0.f ? e : LRELU_ALPHA * e; s += (a4.x > 0) ? __expf(e) : 0.f;
    e = e1i + ev.y; e = e > 0.f ? e : LRELU_ALPHA * e; s += (a4.y > 0) ? __expf(e) : 0.f;
    e = e1i + ev.z; e = e > 0.f ? e : LRELU_ALPHA * e; s += (a4.z > 0) ? __expf(e) : 0.f;
    e = e1i + ev.w; e = e > 0.f ? e : LRELU_ALPHA * e; s += (a4.w > 0) ? __expf(e) : 0.f;
  }
#pragma unroll
  for (int off = 32; off; off >>= 1) s += __shfl_xor(s, off);
  if ((t & 63) == 0) red[t >> 6] = s;
  __syncthreads();
  if (t == 0) sinv[i] = 1.f / (red[0] + red[1] + red[2] + red[3]);
}

// ---------------- fused layer-1: p computed in-kernel -> att1 write + MFMA partial h1 ----------------
// grid (128 row-panels, 8 K-splits) = 1024 blocks (~4/CU resident), 256 thr.
// Block: 64 rows x 256 cols, K-range z*1024..+1024 (16 kt of 64). Per kt:
// thread (pr=t>>2, seg=t&3) computes 16 p = mask*exp(lrelu(e1+e2))*sinv,
// writes att1 fp32 once, drops bf16 into the proven swizzled A-layout; B = bt1
// (4 MB, L2-resident) staged per col; 2x2 waves MFMA 32rx128c each.
__global__ __launch_bounds__(256) void fused_att_agg1_k(
    const unsigned* __restrict__ bits, const float* __restrict__ e1,
    const float* __restrict__ e2, const float* __restrict__ sinv,
    const unsigned short* __restrict__ BT,   // bt1 [256][8192]
    float* __restrict__ att, float* __restrict__ part)  // part [8][8192][256]
{
  __shared__ __align__(16) char As[64 * 128];    // 8 KB
  __shared__ __align__(16) char Bs[256 * 128];   // 32 KB
  int t = threadIdx.x;
  int l = t & 63, w = t >> 6;
  int row0 = blockIdx.x * 64;
  int z = blockIdx.y;
  int wm = w >> 1, wn = w & 1;                  // wave: 32 rows x 128 cols

  f32x4 acc[2][8] = {};

  int pr = t >> 2, seg = t & 3;
  float e1v = e1[row0 + pr];
  float siv = sinv[row0 + pr];
  const unsigned* brow = bits + (size_t)(row0 + pr) * 256 + z * 32;
  const float* e2p = e2 + z * 1024;
  float* arow_att = att + (size_t)(row0 + pr) * 8192 + z * 1024;
  int abase = pr * 128 + seg * 32;
  int aswz = (pr & 7) << 4;

  const unsigned short* bgp = BT + (size_t)t * 8192 + z * 1024;  // col = t
  int bbase = t * 128;
  int bswz = (t & 7) << 4;

  for (int kt = 0; kt < 16; ++kt) {
    __syncthreads();
    { // stage B: col t, 64 k
      const u16x8* src = (const u16x8*)(bgp + kt * 64);
#pragma unroll
      for (int s = 0; s < 8; ++s)
        *(u16x8*)(Bs + ((bbase + s * 16) ^ bswz)) = src[s];
    }
    { // compute p (16 values), write att1, stage bf16 into As
      int j0 = kt * 64 + seg * 16;
      unsigned mb = brow[kt * 2 + (seg >> 1)] >> ((seg & 1) * 16);
      float p[16];
#pragma unroll
      for (int q = 0; q < 4; ++q) {
        float4 ev = *(const float4*)(e2p + j0 + q * 4);
        float e;
        e = e1v + ev.x; e = e > 0.f ? e : LRELU_ALPHA * e;
        p[q*4+0] = ((mb >> (q*4+0)) & 1) ? __expf(e) * siv : 0.f;
        e = e1v + ev.y; e = e > 0.f ? e : LRELU_ALPHA * e;
        p[q*4+1] = ((mb >> (q*4+1)) & 1) ? __expf(e) * siv : 0.f;
        e = e1v + ev.z; e = e > 0.f ? e : LRELU_ALPHA * e;
        p[q*4+2] = ((mb >> (q*4+2)) & 1) ? __expf(e) * siv : 0.f;
        e = e1v + ev.w; e = e > 0.f ? e : LRELU_ALPHA * e;
        p[q*4+3] = ((mb >> (q*4+3)) & 1) ? __expf(e) * siv : 0.f;
        *(float4*)(arow_att + j0 + q * 4) = make_float4(p[q*4+0], p[q*4+1], p[q*4+2], p[q*4+3]);
      }
      u16x8 c0, c1;
#pragma unroll
      for (int q = 0; q < 8; ++q) { c0[q] = f2bf(p[q]); c1[q] = f2bf(p[8 + q]); }
      *(u16x8*)(As + ((abase) ^ aswz)) = c0;
      *(u16x8*)(As + ((abase + 16) ^ aswz)) = c1;
    }
    __syncthreads();
#pragma unroll
    for (int kk = 0; kk < 64; kk += 32) {
      int kb = (kk + (l >> 4) * 8) * 2;
      bf16x8 af[2];
#pragma unroll
      for (int fm = 0; fm < 2; ++fm) {
        int r = wm * 32 + fm * 16 + (l & 15);
        af[fm] = *(const bf16x8*)(As + ((r * 128 + kb) ^ ((r & 7) << 4)));
      }
#pragma unroll
      for (int fn = 0; fn < 8; ++fn) {
        int c = wn * 128 + fn * 16 + (l & 15);
        bf16x8 bf = *(const bf16x8*)(Bs + ((c * 128 + kb) ^ ((c & 7) << 4)));
#pragma unroll
        for (int fm = 0; fm < 2; ++fm)
          acc[fm][fn] = __builtin_amdgcn_mfma_f32_16x16x32_bf16(af[fm], bf, acc[fm][fn], 0, 0, 0);
      }
    }
  }
  // epilogue: write split-K partial. C/D: col=lane&15, row=(lane>>4)*4+reg
#pragma unroll
  for (int fm = 0; fm < 2; ++fm) {
#pragma unroll
    for (int fn = 0; fn < 8; ++fn) {
#pragma unroll
      for (int r = 0; r < 4; ++r) {
        int grow = row0 + wm * 32 + fm * 16 + (l >> 4) * 4 + r;
        int gcol = wn * 128 + fn * 16 + (l & 15);
        part[((size_t)z * 8192 + grow) * 256 + gcol] = acc[fm][fn][r];
      }
    }
  }
}

// ---------------- layer-2 masked softmax (bits mask) ----------------
__global__ __launch_bounds__(256) void att_softmax2_k(
    const unsigned* __restrict__ bits, const float* __restrict__ e1,
    const float* __restrict__ e2, float* __restrict__ att)
{
  __shared__ unsigned bw[256];
  __shared__ float red[4];
  int i = blockIdx.x, t = threadIdx.x;
  bw[t] = bits[(size_t)i * 256 + t];
  float e1i = e1[i];
  __syncthreads();
  float4 vv[8];
  float s = 0.f;
#pragma unroll
  for (int it = 0; it < 8; ++it) {
    int j4 = t + it * 256;
    float4 ev = *(const float4*)(e2 + j4 * 4);
    unsigned wb = bw[j4 >> 3];
    int b0 = (j4 & 7) * 4;
    float e, p0, p1, p2, p3;
    e = e1i + ev.x; e = e > 0.f ? e : LRELU_ALPHA * e; p0 = ((wb >> (b0 + 0)) & 1) ? __expf(e) : 0.f;
    e = e1i + ev.y; e = e > 0.f ? e : LRELU_ALPHA * e; p1 = ((wb >> (b0 + 1)) & 1) ? __expf(e) : 0.f;
    e = e1i + ev.z; e = e > 0.f ? e : LRELU_ALPHA * e; p2 = ((wb >> (b0 + 2)) & 1) ? __expf(e) : 0.f;
    e = e1i + ev.w; e = e > 0.f ? e : LRELU_ALPHA * e; p3 = ((wb >> (b0 + 3)) & 1) ? __expf(e) : 0.f;
    vv[it] = make_float4(p0, p1, p2, p3);
    s += (p0 + p1) + (p2 + p3);
  }
#pragma unroll
  for (int off = 32; off; off >>= 1) s += __shfl_xor(s, off);
  if ((t & 63) == 0) red[t >> 6] = s;
  __syncthreads();
  s = red[0] + red[1] + red[2] + red[3];
  float inv = 1.f / s;
  float4* orow = (float4*)(att + (size_t)i * 8192);
#pragma unroll
  for (int it = 0; it < 8; ++it) {
    float4 p = vv[it];
    p.x *= inv; p.y *= inv; p.z *= inv; p.w *= inv;
    orow[t + it * 256] = p;
  }
}

// ---------------- MFMA bf16 GEMM (layer 2): BM=64, BN=16, split-K ----------------
template<int BN, int SPLITK, int EPI>
__global__ __launch_bounds__(256) void gemm_mfma_k(
    const float* __restrict__ A, const unsigned short* __restrict__ BT,
    float* __restrict__ Cout, int M, int K, int ldc)
{
  constexpr int BM = 64, BK = 64;
  constexpr int WN = (BN == 64) ? 2 : 1;
  constexpr int WM = 4 / WN;
  constexpr int WROWS = BM / WM;
  constexpr int WCOLS = BN / WN;
  constexpr int FM = WROWS / 16;
  constexpr int FN = WCOLS / 16;
  __shared__ __align__(16) char As[BM * BK * 2];
  __shared__ __align__(16) char Bs[BN * BK * 2];
  int t = threadIdx.x;
  int row0 = blockIdx.x * BM;
  int col0 = blockIdx.y * BN;
  int ktiles = K / BK;
  int kt0 = blockIdx.z * (ktiles / SPLITK);
  int kt1 = kt0 + ktiles / SPLITK;
  int w = t >> 6, l = t & 63;
  int wm = w / WN, wn = w % WN;

  f32x4 acc[FM][FN] = {};

  int ar = t >> 2, aseg = t & 3;
  int swzA = (ar & 7) << 4;

  for (int kt = kt0; kt < kt1; ++kt) {
    __syncthreads();
    {
      const float4* src = (const float4*)(A + (size_t)(row0 + ar) * K + kt * BK + aseg * 16);
      float4 v0 = src[0], v1 = src[1], v2 = src[2], v3 = src[3];
      u16x8 c0, c1;
      c0[0]=f2bf(v0.x); c0[1]=f2bf(v0.y); c0[2]=f2bf(v0.z); c0[3]=f2bf(v0.w);
      c0[4]=f2bf(v1.x); c0[5]=f2bf(v1.y); c0[6]=f2bf(v1.z); c0[7]=f2bf(v1.w);
      c1[0]=f2bf(v2.x); c1[1]=f2bf(v2.y); c1[2]=f2bf(v2.z); c1[3]=f2bf(v2.w);
      c1[4]=f2bf(v3.x); c1[5]=f2bf(v3.y); c1[6]=f2bf(v3.z); c1[7]=f2bf(v3.w);
      int base = ar * 128 + aseg * 32;
      *(u16x8*)(As + ((base) ^ swzA)) = c0;
      *(u16x8*)(As + ((base + 16) ^ swzA)) = c1;
    }
    if (BN == 64) {
      int br = t >> 2, seg = t & 3;
      const u16x8* src = (const u16x8*)(BT + (size_t)(col0 + br) * K + kt * BK + seg * 16);
      u16x8 b0 = src[0], b1 = src[1];
      int base = br * 128 + seg * 32;
      int swz = (br & 7) << 4;
      *(u16x8*)(Bs + ((base) ^ swz)) = b0;
      *(u16x8*)(Bs + ((base + 16) ^ swz)) = b1;
    } else {
      int br = t >> 4, seg = t & 15;
      const u16x4* src = (const u16x4*)(BT + (size_t)(col0 + br) * K + kt * BK + seg * 4);
      u16x4 b0 = src[0];
      int base = br * 128 + seg * 8;
      int swz = (br & 7) << 4;
      *(u16x4*)(Bs + (base ^ swz)) = b0;
    }
    __syncthreads();
#pragma unroll
    for (int kk = 0; kk < BK; kk += 32) {
      bf16x8 af[FM], bfr[FN];
      int kb = (kk + (l >> 4) * 8) * 2;
#pragma unroll
      for (int fm = 0; fm < FM; ++fm) {
        int r = wm * WROWS + fm * 16 + (l & 15);
        af[fm] = *(const bf16x8*)(As + ((r * 128 + kb) ^ ((r & 7) << 4)));
      }
#pragma unroll
      for (int fn = 0; fn < FN; ++fn) {
        int c = wn * WCOLS + fn * 16 + (l & 15);
        bfr[fn] = *(const bf16x8*)(Bs + ((c * 128 + kb) ^ ((c & 7) << 4)));
      }
#pragma unroll
      for (int fm = 0; fm < FM; ++fm)
#pragma unroll
        for (int fn = 0; fn < FN; ++fn)
          acc[fm][fn] = __builtin_amdgcn_mfma_f32_16x16x32_bf16(af[fm], bfr[fn], acc[fm][fn], 0, 0, 0);
    }
  }
#pragma unroll
  for (int fm = 0; fm < FM; ++fm) {
#pragma unroll
    for (int fn = 0; fn < FN; ++fn) {
#pragma unroll
      for (int r = 0; r < 4; ++r) {
        int grow = row0 + wm * WROWS + fm * 16 + (l >> 4) * 4 + r;
        int gcol = col0 + wn * WCOLS + fn * 16 + (l & 15);
        float v = acc[fm][fn][r];
        if (EPI == 1) v = v > 0.f ? v : expm1f(v);
        size_t idx = (SPLITK > 1)
          ? ((size_t)blockIdx.z * M + grow) * ldc + gcol
          : (size_t)grow * ldc + gcol;
        Cout[idx] = v;
      }
    }
  }
}

// ---------------- small GEMM: Wh2[M][16] = h1[M][256] @ W2[256][16] ----------------
__global__ __launch_bounds__(256) void gemm_small_k(
    const float* __restrict__ A, const float* __restrict__ B,
    float* __restrict__ C, int K, int Ncols)
{
  int t = threadIdx.x;
  int r = blockIdx.x * 16 + (t >> 4);
  int c = t & 15;
  const float* arow = A + (size_t)r * K;
  float acc = 0.f;
#pragma unroll 8
  for (int k = 0; k < K; ++k)
    acc = fmaf(arow[k], B[k * Ncols + c], acc);
  C[(size_t)r * Ncols + c] = acc;
}

// ---------------- split-K reduce + ELU (8 partials) ----------------
__global__ void reduce_elu8_k(const float* __restrict__ part, float* __restrict__ out, int total)
{
  int i = blockIdx.x * 256 + threadIdx.x;
  if (i < total) {
    float s = 0.f;
#pragma unroll
    for (int z = 0; z < 8; ++z)
      s += part[(size_t)z * total + i];
    out[i] = s > 0.f ? s : expm1f(s);
  }
}

// ---------------- split-K reduce + sigmoid (16 partials) ----------------
__global__ void reduce_sig16_k(const float* __restrict__ part, float* __restrict__ out, int total)
{
  int i = blockIdx.x * 256 + threadIdx.x;
  if (i < total) {
    float s = 0.f;
#pragma unroll
    for (int z = 0; z < 16; ++z)
      s += part[(size_t)z * total + i];
    out[i] = 1.f / (1.f + __expf(-s));
  }
}

extern "C" void kernel_launch(void* const* d_in, const int* in_sizes, int n_in,
                              void* d_out, int out_size, void* d_ws, size_t ws_size,
                              hipStream_t stream)
{
  const float* x   = (const float*)d_in[0];
  const int*   adj = (const int*)d_in[1];
  const float* W1  = (const float*)d_in[2];
  const float* a1  = (const float*)d_in[3];
  const float* W2  = (const float*)d_in[4];
  const float* a2  = (const float*)d_in[5];

  float* out  = (float*)d_out;                 // [8192*16]
  float* h1   = out + 131072;                  // [8192*256]
  float* att1 = h1 + 2097152;                  // [8192*8192]
  float* att2 = att1 + 67108864;               // [8192*8192]

  float* ws = (float*)d_ws;
  float* wh1 = ws;                                            // 2097152 f
  unsigned short* bt1 = (unsigned short*)(wh1 + 2097152);     // 2097152 u16
  float* e1a = wh1 + 2097152 + 1048576;
  float* e2a = e1a + 8192;
  float* sinv1 = e2a + 8192;
  float* wh2 = sinv1 + 8192;                                  // 131072 f
  unsigned short* bt2 = (unsigned short*)(wh2 + 131072);      // 131072 u16
  float* e1b = wh2 + 131072 + 65536;
  float* e2b = e1b + 8192;
  float* part2 = e2b + 8192;                                  // 16*131072 = 2097152 f
  unsigned* bits = (unsigned*)(part2 + 2097152);              // 2097152 u32
  float* part1 = (float*)(bits + 2097152);                    // 8*2097152 = 16777216 f

  // ---- layer 1 ----
  gemm_f32_k<<<dim3(64, 4), 256, 0, stream>>>(x, W1, wh1, 8192, 512, 256);
  calc_e_k<<<2048, 256, 0, stream>>>(wh1, a1, e1a, e2a, 256);
  transpose_bf16_k<<<dim3(8, 256), dim3(32, 8), 0, stream>>>(wh1, bt1, 8192, 256);
  rowsum_pack_k<<<8192, 256, 0, stream>>>(adj, e1a, e2a, bits, sinv1);
  fused_att_agg1_k<<<dim3(128, 8), 256, 0, stream>>>(bits, e1a, e2a, sinv1, bt1, att1, part1);
  reduce_elu8_k<<<8192, 256, 0, stream>>>(part1, h1, 2097152);

  // ---- layer 2 ----
  gemm_small_k<<<512, 256, 0, stream>>>(h1, W2, wh2, 256, 16);
  calc_e_k<<<2048, 256, 0, stream>>>(wh2, a2, e1b, e2b, 16);
  transpose_bf16_k<<<dim3(1, 256), dim3(32, 8), 0, stream>>>(wh2, bt2, 8192, 16);
  att_softmax2_k<<<8192, 256, 0, stream>>>(bits, e1b, e2b, att2);
  gemm_mfma_k<16, 16, 0><<<dim3(128, 1, 16), 256, 0, stream>>>(att2, bt2, part2, 8192, 8192, 16);
  reduce_sig16_k<<<512, 256, 0, stream>>>(part2, out, 131072);
}

// Round 12
// 440.266 us; speedup vs baseline: 1.2860x; 1.2860x over previous
//
#include <hip/hip_runtime.h>
#include <hip/hip_bf16.h>

#define LRELU_ALPHA 0.2f

typedef __attribute__((ext_vector_type(8))) __bf16 bf16x8;
typedef __attribute__((ext_vector_type(4))) float f32x4;
typedef __attribute__((ext_vector_type(8))) unsigned short u16x8;
typedef __attribute__((ext_vector_type(4))) unsigned short u16x4;

__device__ __forceinline__ unsigned short f2bf(float f) {
  unsigned int u = __float_as_uint(f);
  u += 0x7fffu + ((u >> 16) & 1u);   // round-to-nearest-even
  return (unsigned short)(u >> 16);
}

// ---------------- fp32 tiled GEMM: wh1 = x @ W1 ----------------
__global__ __launch_bounds__(256) void gemm_f32_k(
    const float* __restrict__ A, const float* __restrict__ B,
    float* __restrict__ C, int M, int K, int Ncols)
{
  __shared__ float As[128][17];
  __shared__ float Bs[16][65];
  int t = threadIdx.x;
  int row0 = blockIdx.x * 128;
  int col0 = blockIdx.y * 64;
  int ty = t >> 4, tx = t & 15;
  float acc[8][4];
#pragma unroll
  for (int i = 0; i < 8; ++i)
#pragma unroll
    for (int j = 0; j < 4; ++j) acc[i][j] = 0.f;

  for (int kt = 0; kt < K; kt += 16) {
    __syncthreads();
    {
      int r = t >> 1, h = t & 1;
      const float4* src = (const float4*)(A + (size_t)(row0 + r) * K + kt + h * 8);
      float4 v0 = src[0], v1 = src[1];
      float* dst = &As[r][h * 8];
      dst[0]=v0.x; dst[1]=v0.y; dst[2]=v0.z; dst[3]=v0.w;
      dst[4]=v1.x; dst[5]=v1.y; dst[6]=v1.z; dst[7]=v1.w;
    }
    {
      int kr = t >> 4, seg = t & 15;
      const float4* src = (const float4*)(B + (size_t)(kt + kr) * Ncols + col0 + seg * 4);
      float4 v = src[0];
      float* dst = &Bs[kr][seg * 4];
      dst[0]=v.x; dst[1]=v.y; dst[2]=v.z; dst[3]=v.w;
    }
    __syncthreads();
#pragma unroll
    for (int k = 0; k < 16; ++k) {
      float bb[4];
#pragma unroll
      for (int j = 0; j < 4; ++j) bb[j] = Bs[k][tx * 4 + j];
#pragma unroll
      for (int i = 0; i < 8; ++i) {
        float aa = As[ty * 8 + i][k];
#pragma unroll
        for (int j = 0; j < 4; ++j) acc[i][j] = fmaf(aa, bb[j], acc[i][j]);
      }
    }
  }
#pragma unroll
  for (int i = 0; i < 8; ++i) {
    float4 v = make_float4(acc[i][0], acc[i][1], acc[i][2], acc[i][3]);
    *(float4*)(C + (size_t)(row0 + ty * 8 + i) * Ncols + col0 + tx * 4) = v;
  }
}

// ---------------- e1/e2 vectors: wave per row ----------------
__global__ __launch_bounds__(256) void calc_e_k(
    const float* __restrict__ Wh, const float* __restrict__ a,
    float* __restrict__ e1, float* __restrict__ e2, int F)
{
  int row = blockIdx.x * 4 + (threadIdx.x >> 6);
  int l = threadIdx.x & 63;
  const float* r = Wh + (size_t)row * F;
  float s1 = 0.f, s2 = 0.f;
  for (int f = l; f < F; f += 64) {
    float v = r[f];
    s1 += v * a[f];
    s2 += v * a[F + f];
  }
#pragma unroll
  for (int off = 32; off; off >>= 1) {
    s1 += __shfl_down(s1, off);
    s2 += __shfl_down(s2, off);
  }
  if (l == 0) { e1[row] = s1; e2[row] = s2; }
}

// ---------------- transpose + fp32->bf16: out[c][r] = bf16(in[r][c]) ----------------
__global__ void transpose_bf16_k(const float* __restrict__ in, unsigned short* __restrict__ out,
                                 int R, int Cc)
{
  __shared__ float tile[32][33];
  int tx = threadIdx.x, ty = threadIdx.y;
  int c0 = blockIdx.x * 32, r0 = blockIdx.y * 32;
  int c = c0 + tx;
  if (c < Cc) {
    for (int i = ty; i < 32; i += 8)
      tile[i][tx] = in[(size_t)(r0 + i) * Cc + c];
  }
  __syncthreads();
  int r = r0 + tx;
  for (int i = ty; i < 32; i += 8) {
    int cc = c0 + i;
    if (cc < Cc)
      out[(size_t)cc * R + r] = f2bf(tile[tx][i]);
  }
}

// ---------------- layer-1 masked softmax + inline adj bit-pack + bf16 dual write ----------------
// One block per row. int4 adj reads, float4 att stores, single-pass (no
// max-shift: verified identical numerics R3-R11). Also writes att1b (bf16
// shadow) so gemm1's A staging is pure bf16 (no f2bf, half the read bytes).
__global__ __launch_bounds__(256) void att_softmax1_k(
    const int* __restrict__ adj, const float* __restrict__ e1,
    const float* __restrict__ e2, float* __restrict__ att,
    unsigned short* __restrict__ attb, unsigned* __restrict__ bits)
{
  __shared__ float red[4];
  int i = blockIdx.x, t = threadIdx.x;
  const int4* arow = (const int4*)(adj + (size_t)i * 8192);
  unsigned* brow = bits + (size_t)i * 256;
  float e1i = e1[i];
  float4 vv[8];
  float s = 0.f;
#pragma unroll
  for (int it = 0; it < 8; ++it) {
    int j4 = t + it * 256;               // int4/float4 index
    int4 a4 = arow[j4];
    float4 ev = *(const float4*)(e2 + j4 * 4);
    unsigned n = (unsigned)(a4.x > 0) | ((unsigned)(a4.y > 0) << 1)
               | ((unsigned)(a4.z > 0) << 2) | ((unsigned)(a4.w > 0) << 3);
    unsigned v = n << ((t & 7) * 4);
    v |= __shfl_xor(v, 1);
    v |= __shfl_xor(v, 2);
    v |= __shfl_xor(v, 4);
    if ((t & 7) == 0) brow[it * 32 + (t >> 3)] = v;
    float e, p0, p1, p2, p3;
    e = e1i + ev.x; e = e > 0.f ? e : LRELU_ALPHA * e; p0 = (a4.x > 0) ? __expf(e) : 0.f;
    e = e1i + ev.y; e = e > 0.f ? e : LRELU_ALPHA * e; p1 = (a4.y > 0) ? __expf(e) : 0.f;
    e = e1i + ev.z; e = e > 0.f ? e : LRELU_ALPHA * e; p2 = (a4.z > 0) ? __expf(e) : 0.f;
    e = e1i + ev.w; e = e > 0.f ? e : LRELU_ALPHA * e; p3 = (a4.w > 0) ? __expf(e) : 0.f;
    vv[it] = make_float4(p0, p1, p2, p3);
    s += (p0 + p1) + (p2 + p3);
  }
#pragma unroll
  for (int off = 32; off; off >>= 1) s += __shfl_xor(s, off);
  if ((t & 63) == 0) red[t >> 6] = s;
  __syncthreads();
  s = red[0] + red[1] + red[2] + red[3];
  float inv = 1.f / s;
  float4* orow = (float4*)(att + (size_t)i * 8192);
  unsigned short* obrow = attb + (size_t)i * 8192;
#pragma unroll
  for (int it = 0; it < 8; ++it) {
    int j4 = t + it * 256;
    float4 p = vv[it];
    p.x *= inv; p.y *= inv; p.z *= inv; p.w *= inv;
    orow[j4] = p;
    u16x4 b;
    b[0] = f2bf(p.x); b[1] = f2bf(p.y); b[2] = f2bf(p.z); b[3] = f2bf(p.w);
    *(u16x4*)(obrow + j4 * 4) = b;
  }
}

// ---------------- layer-2 masked softmax (bits mask) ----------------
__global__ __launch_bounds__(256) void att_softmax2_k(
    const unsigned* __restrict__ bits, const float* __restrict__ e1,
    const float* __restrict__ e2, float* __restrict__ att)
{
  __shared__ unsigned bw[256];
  __shared__ float red[4];
  int i = blockIdx.x, t = threadIdx.x;
  bw[t] = bits[(size_t)i * 256 + t];
  float e1i = e1[i];
  __syncthreads();
  float4 vv[8];
  float s = 0.f;
#pragma unroll
  for (int it = 0; it < 8; ++it) {
    int j4 = t + it * 256;
    float4 ev = *(const float4*)(e2 + j4 * 4);
    unsigned wb = bw[j4 >> 3];
    int b0 = (j4 & 7) * 4;
    float e, p0, p1, p2, p3;
    e = e1i + ev.x; e = e > 0.f ? e : LRELU_ALPHA * e; p0 = ((wb >> (b0 + 0)) & 1) ? __expf(e) : 0.f;
    e = e1i + ev.y; e = e > 0.f ? e : LRELU_ALPHA * e; p1 = ((wb >> (b0 + 1)) & 1) ? __expf(e) : 0.f;
    e = e1i + ev.z; e = e > 0.f ? e : LRELU_ALPHA * e; p2 = ((wb >> (b0 + 2)) & 1) ? __expf(e) : 0.f;
    e = e1i + ev.w; e = e > 0.f ? e : LRELU_ALPHA * e; p3 = ((wb >> (b0 + 3)) & 1) ? __expf(e) : 0.f;
    vv[it] = make_float4(p0, p1, p2, p3);
    s += (p0 + p1) + (p2 + p3);
  }
#pragma unroll
  for (int off = 32; off; off >>= 1) s += __shfl_xor(s, off);
  if ((t & 63) == 0) red[t >> 6] = s;
  __syncthreads();
  s = red[0] + red[1] + red[2] + red[3];
  float inv = 1.f / s;
  float4* orow = (float4*)(att + (size_t)i * 8192);
#pragma unroll
  for (int it = 0; it < 8; ++it) {
    float4 p = vv[it];
    p.x *= inv; p.y *= inv; p.z *= inv; p.w *= inv;
    orow[t + it * 256] = p;
  }
}

// ---------------- MFMA bf16 GEMM (layer 1): part1[z] = att1b @ bt1^T ----------------
// R9 structure (BM=64, BN=64, 2x2 waves, splitK=4) but A is bf16: staging is
// 2 u16x8 loads + 2 swizzled LDS stores per thread (no f2bf, half read bytes).
__global__ __launch_bounds__(256) void gemm_mfma1b_k(
    const unsigned short* __restrict__ A,    // att1b [8192][8192] bf16
    const unsigned short* __restrict__ BT,   // bt1 [256][8192] bf16
    float* __restrict__ part)                // [4][8192][256]
{
  constexpr int BM = 64, BN = 64, BK = 64;
  __shared__ __align__(16) char As[BM * 128];
  __shared__ __align__(16) char Bs[BN * 128];
  int t = threadIdx.x;
  int row0 = blockIdx.x * BM;
  int col0 = blockIdx.y * BN;
  int z = blockIdx.z;
  int kt0 = z * 32, kt1 = kt0 + 32;
  int w = t >> 6, l = t & 63;
  int wm = w >> 1, wn = w & 1;

  f32x4 acc[2][2] = {};

  int ar = t >> 2, aseg = t & 3;   // A: 64 rows x 4 segs of 16 bf16
  int swzA = (ar & 7) << 4;
  const unsigned short* agp = A + (size_t)(row0 + ar) * 8192 + aseg * 16;

  for (int kt = kt0; kt < kt1; ++kt) {
    __syncthreads();
    { // stage A (bf16 direct, swizzled)
      const u16x8* src = (const u16x8*)(agp + kt * BK);
      u16x8 c0 = src[0], c1 = src[1];
      int base = ar * 128 + aseg * 32;
      *(u16x8*)(As + ((base) ^ swzA)) = c0;
      *(u16x8*)(As + ((base + 16) ^ swzA)) = c1;
    }
    { // stage B: 64 rows x 64 bf16
      int br = t >> 2, seg = t & 3;
      const u16x8* src = (const u16x8*)(BT + (size_t)(col0 + br) * 8192 + kt * BK + seg * 16);
      u16x8 b0 = src[0], b1 = src[1];
      int base = br * 128 + seg * 32;
      int swz = (br & 7) << 4;
      *(u16x8*)(Bs + ((base) ^ swz)) = b0;
      *(u16x8*)(Bs + ((base + 16) ^ swz)) = b1;
    }
    __syncthreads();
#pragma unroll
    for (int kk = 0; kk < BK; kk += 32) {
      bf16x8 af[2], bfr[2];
      int kb = (kk + (l >> 4) * 8) * 2;
#pragma unroll
      for (int fm = 0; fm < 2; ++fm) {
        int r = wm * 32 + fm * 16 + (l & 15);
        af[fm] = *(const bf16x8*)(As + ((r * 128 + kb) ^ ((r & 7) << 4)));
      }
#pragma unroll
      for (int fn = 0; fn < 2; ++fn) {
        int c = wn * 32 + fn * 16 + (l & 15);
        bfr[fn] = *(const bf16x8*)(Bs + ((c * 128 + kb) ^ ((c & 7) << 4)));
      }
#pragma unroll
      for (int fm = 0; fm < 2; ++fm)
#pragma unroll
        for (int fn = 0; fn < 2; ++fn)
          acc[fm][fn] = __builtin_amdgcn_mfma_f32_16x16x32_bf16(af[fm], bfr[fn], acc[fm][fn], 0, 0, 0);
    }
  }
  // epilogue: C/D layout col=lane&15, row=(lane>>4)*4+reg
#pragma unroll
  for (int fm = 0; fm < 2; ++fm) {
#pragma unroll
    for (int fn = 0; fn < 2; ++fn) {
#pragma unroll
      for (int r = 0; r < 4; ++r) {
        int grow = row0 + wm * 32 + fm * 16 + (l >> 4) * 4 + r;
        int gcol = col0 + wn * 32 + fn * 16 + (l & 15);
        part[((size_t)z * 8192 + grow) * 256 + gcol] = acc[fm][fn][r];
      }
    }
  }
}

// ---------------- MFMA bf16 GEMM (layer 2): R9-verbatim fp32-A, BN=16, splitK ----------------
template<int BN, int SPLITK, int EPI>
__global__ __launch_bounds__(256) void gemm_mfma_k(
    const float* __restrict__ A, const unsigned short* __restrict__ BT,
    float* __restrict__ Cout, int M, int K, int ldc)
{
  constexpr int BM = 64, BK = 64;
  constexpr int WN = (BN == 64) ? 2 : 1;
  constexpr int WM = 4 / WN;
  constexpr int WROWS = BM / WM;
  constexpr int WCOLS = BN / WN;
  constexpr int FM = WROWS / 16;
  constexpr int FN = WCOLS / 16;
  __shared__ __align__(16) char As[BM * BK * 2];
  __shared__ __align__(16) char Bs[BN * BK * 2];
  int t = threadIdx.x;
  int row0 = blockIdx.x * BM;
  int col0 = blockIdx.y * BN;
  int ktiles = K / BK;
  int kt0 = blockIdx.z * (ktiles / SPLITK);
  int kt1 = kt0 + ktiles / SPLITK;
  int w = t >> 6, l = t & 63;
  int wm = w / WN, wn = w % WN;

  f32x4 acc[FM][FN] = {};

  int ar = t >> 2, aseg = t & 3;
  int swzA = (ar & 7) << 4;

  for (int kt = kt0; kt < kt1; ++kt) {
    __syncthreads();
    {
      const float4* src = (const float4*)(A + (size_t)(row0 + ar) * K + kt * BK + aseg * 16);
      float4 v0 = src[0], v1 = src[1], v2 = src[2], v3 = src[3];
      u16x8 c0, c1;
      c0[0]=f2bf(v0.x); c0[1]=f2bf(v0.y); c0[2]=f2bf(v0.z); c0[3]=f2bf(v0.w);
      c0[4]=f2bf(v1.x); c0[5]=f2bf(v1.y); c0[6]=f2bf(v1.z); c0[7]=f2bf(v1.w);
      c1[0]=f2bf(v2.x); c1[1]=f2bf(v2.y); c1[2]=f2bf(v2.z); c1[3]=f2bf(v2.w);
      c1[4]=f2bf(v3.x); c1[5]=f2bf(v3.y); c1[6]=f2bf(v3.z); c1[7]=f2bf(v3.w);
      int base = ar * 128 + aseg * 32;
      *(u16x8*)(As + ((base) ^ swzA)) = c0;
      *(u16x8*)(As + ((base + 16) ^ swzA)) = c1;
    }
    if (BN == 64) {
      int br = t >> 2, seg = t & 3;
      const u16x8* src = (const u16x8*)(BT + (size_t)(col0 + br) * K + kt * BK + seg * 16);
      u16x8 b0 = src[0], b1 = src[1];
      int base = br * 128 + seg * 32;
      int swz = (br & 7) << 4;
      *(u16x8*)(Bs + ((base) ^ swz)) = b0;
      *(u16x8*)(Bs + ((base + 16) ^ swz)) = b1;
    } else {
      int br = t >> 4, seg = t & 15;
      const u16x4* src = (const u16x4*)(BT + (size_t)(col0 + br) * K + kt * BK + seg * 4);
      u16x4 b0 = src[0];
      int base = br * 128 + seg * 8;
      int swz = (br & 7) << 4;
      *(u16x4*)(Bs + (base ^ swz)) = b0;
    }
    __syncthreads();
#pragma unroll
    for (int kk = 0; kk < BK; kk += 32) {
      bf16x8 af[FM], bfr[FN];
      int kb = (kk + (l >> 4) * 8) * 2;
#pragma unroll
      for (int fm = 0; fm < FM; ++fm) {
        int r = wm * WROWS + fm * 16 + (l & 15);
        af[fm] = *(const bf16x8*)(As + ((r * 128 + kb) ^ ((r & 7) << 4)));
      }
#pragma unroll
      for (int fn = 0; fn < FN; ++fn) {
        int c = wn * WCOLS + fn * 16 + (l & 15);
        bfr[fn] = *(const bf16x8*)(Bs + ((c * 128 + kb) ^ ((c & 7) << 4)));
      }
#pragma unroll
      for (int fm = 0; fm < FM; ++fm)
#pragma unroll
        for (int fn = 0; fn < FN; ++fn)
          acc[fm][fn] = __builtin_amdgcn_mfma_f32_16x16x32_bf16(af[fm], bfr[fn], acc[fm][fn], 0, 0, 0);
    }
  }
#pragma unroll
  for (int fm = 0; fm < FM; ++fm) {
#pragma unroll
    for (int fn = 0; fn < FN; ++fn) {
#pragma unroll
      for (int r = 0; r < 4; ++r) {
        int grow = row0 + wm * WROWS + fm * 16 + (l >> 4) * 4 + r;
        int gcol = col0 + wn * WCOLS + fn * 16 + (l & 15);
        float v = acc[fm][fn][r];
        if (EPI == 1) v = v > 0.f ? v : expm1f(v);
        size_t idx = (SPLITK > 1)
          ? ((size_t)blockIdx.z * M + grow) * ldc + gcol
          : (size_t)grow * ldc + gcol;
        Cout[idx] = v;
      }
    }
  }
}

// ---------------- small GEMM: Wh2[M][16] = h1[M][256] @ W2[256][16] ----------------
__global__ __launch_bounds__(256) void gemm_small_k(
    const float* __restrict__ A, const float* __restrict__ B,
    float* __restrict__ C, int K, int Ncols)
{
  int t = threadIdx.x;
  int r = blockIdx.x * 16 + (t >> 4);
  int c = t & 15;
  const float* arow = A + (size_t)r * K;
  float acc = 0.f;
#pragma unroll 8
  for (int k = 0; k < K; ++k)
    acc = fmaf(arow[k], B[k * Ncols + c], acc);
  C[(size_t)r * Ncols + c] = acc;
}

// ---------------- split-K reduce + ELU (4 partials) ----------------
__global__ void reduce_elu_k(const float* __restrict__ part, float* __restrict__ out, int total)
{
  int i = blockIdx.x * 256 + threadIdx.x;
  if (i < total) {
    float s = (part[i] + part[total + i]) + (part[2 * (size_t)total + i] + part[3 * (size_t)total + i]);
    out[i] = s > 0.f ? s : expm1f(s);
  }
}

// ---------------- split-K reduce + sigmoid (4 partials) ----------------
__global__ void reduce_sig_k(const float* __restrict__ part, float* __restrict__ out, int total)
{
  int i = blockIdx.x * 256 + threadIdx.x;
  if (i < total) {
    float s = part[i] + part[total + i] + part[2 * (size_t)total + i] + part[3 * (size_t)total + i];
    out[i] = 1.f / (1.f + __expf(-s));
  }
}

extern "C" void kernel_launch(void* const* d_in, const int* in_sizes, int n_in,
                              void* d_out, int out_size, void* d_ws, size_t ws_size,
                              hipStream_t stream)
{
  const float* x   = (const float*)d_in[0];
  const int*   adj = (const int*)d_in[1];
  const float* W1  = (const float*)d_in[2];
  const float* a1  = (const float*)d_in[3];
  const float* W2  = (const float*)d_in[4];
  const float* a2  = (const float*)d_in[5];

  float* out  = (float*)d_out;                 // [8192*16]
  float* h1   = out + 131072;                  // [8192*256]
  float* att1 = h1 + 2097152;                  // [8192*8192]
  float* att2 = att1 + 67108864;               // [8192*8192]

  float* ws = (float*)d_ws;
  float* wh1 = ws;                                            // 2097152 f
  unsigned short* bt1 = (unsigned short*)(wh1 + 2097152);     // 2097152 u16
  float* e1a = wh1 + 2097152 + 1048576;
  float* e2a = e1a + 8192;
  float* wh2 = e2a + 8192;                                    // 131072 f
  unsigned short* bt2 = (unsigned short*)(wh2 + 131072);      // 131072 u16
  float* e1b = wh2 + 131072 + 65536;
  float* e2b = e1b + 8192;
  float* part2 = e2b + 8192;                                  // 4*131072 f
  unsigned* bits = (unsigned*)(part2 + 524288);               // 2097152 u32
  float* part1 = (float*)(bits + 2097152);                    // 4*2097152 f
  unsigned short* att1b = (unsigned short*)(part1 + 8388608); // 67108864 u16

  // ---- layer 1 ----
  gemm_f32_k<<<dim3(64, 4), 256, 0, stream>>>(x, W1, wh1, 8192, 512, 256);
  calc_e_k<<<2048, 256, 0, stream>>>(wh1, a1, e1a, e2a, 256);
  transpose_bf16_k<<<dim3(8, 256), dim3(32, 8), 0, stream>>>(wh1, bt1, 8192, 256);
  att_softmax1_k<<<8192, 256, 0, stream>>>(adj, e1a, e2a, att1, att1b, bits);
  gemm_mfma1b_k<<<dim3(128, 4, 4), 256, 0, stream>>>(att1b, bt1, part1);
  reduce_elu_k<<<8192, 256, 0, stream>>>(part1, h1, 2097152);

  // ---- layer 2 ----
  gemm_small_k<<<512, 256, 0, stream>>>(h1, W2, wh2, 256, 16);
  calc_e_k<<<2048, 256, 0, stream>>>(wh2, a2, e1b, e2b, 16);
  transpose_bf16_k<<<dim3(1, 256), dim3(32, 8), 0, stream>>>(wh2, bt2, 8192, 16);
  att_softmax2_k<<<8192, 256, 0, stream>>>(bits, e1b, e2b, att2);
  gemm_mfma_k<16, 4, 0><<<dim3(128, 1, 4), 256, 0, stream>>>(att2, bt2, part2, 8192, 8192, 16);
  reduce_sig_k<<<512, 256, 0, stream>>>(part2, out, 131072);
}